// Round 1
// baseline (414.635 us; speedup 1.0000x reference)
//
#include <hip/hip_runtime.h>

#define BS 4
#define NF 512
#define HW 4096
#define C8 64

typedef unsigned short bfu;                                    // raw bf16 bits
typedef __attribute__((ext_vector_type(8))) short bf16x8;      // MFMA A/B frag (4 VGPRs)
typedef __attribute__((ext_vector_type(4))) float f32x4;       // MFMA C/D frag

static __device__ __forceinline__ bfu f2bu(float v) {
    union { unsigned int u; float f; } c; c.f = v;
    unsigned int u = c.u;
    u = u + 0x7FFFu + ((u >> 16) & 1u);   // round-to-nearest-even
    return (bfu)(u >> 16);
}
static __device__ __forceinline__ float bu2f(bfu v) {
    union { unsigned int u; float f; } c; c.u = ((unsigned int)v) << 16;
    return c.f;
}

// ---------------- k0: x fp32 [b][c][n] -> xt bf16 [b][n][c] ----------------
__global__ __launch_bounds__(256) void k0_xt(const float* __restrict__ x, bfu* __restrict__ xt)
{
    __shared__ float T[64][68];                 // pad 68: float4 aligned, ~2-way banks
    const int t  = threadIdx.x;
    const int n0 = blockIdx.x * 64;
    const int c0 = blockIdx.y * 64;
    const int b  = blockIdx.z;

    #pragma unroll
    for (int u = 0; u < 4; u++) {
        int f4 = u * 256 + t;
        int cc = f4 >> 4;
        int n4 = (f4 & 15) << 2;
        float4 v = *(const float4*)(x + ((size_t)(b * NF + c0 + cc)) * HW + n0 + n4);
        *(float4*)&T[cc][n4] = v;
    }
    __syncthreads();
    #pragma unroll
    for (int u = 0; u < 2; u++) {
        int e8 = u * 256 + t;
        int nn = e8 >> 3;
        int c8 = (e8 & 7) << 3;
        union { int4 i4; bfu h[8]; } pk;
        #pragma unroll
        for (int q = 0; q < 8; q++) pk.h[q] = f2bu(T[c8 + q][nn]);
        *(int4*)(xt + ((size_t)(b * HW + n0 + nn)) * NF + c0 + c8) = pk.i4;
    }
}

// ---------------- k0b: Wq|Wk|Wv -> Wb bf16 [640][512]; biases -> bcat[640] ----------------
__global__ __launch_bounds__(256) void k0_w(const float* __restrict__ Wq, const float* __restrict__ bq,
                                            const float* __restrict__ Wk, const float* __restrict__ bk,
                                            const float* __restrict__ Wv, const float* __restrict__ bv,
                                            bfu* __restrict__ Wb, float* __restrict__ bcat)
{
    const int o = blockIdx.x;                   // 0..639
    const int t = threadIdx.x;
    const float* src; float bias;
    if (o < 64)       { src = Wq + (size_t)o * NF;          bias = bq[o]; }
    else if (o < 128) { src = Wk + (size_t)(o - 64) * NF;   bias = bk[o - 64]; }
    else              { src = Wv + (size_t)(o - 128) * NF;  bias = bv[o - 128]; }
    float2 v = *(const float2*)(src + t * 2);
    Wb[(size_t)o * NF + t * 2 + 0] = f2bu(v.x);
    Wb[(size_t)o * NF + t * 2 + 1] = f2bu(v.y);
    if (t == 0) bcat[o] = bias;
}

// ---------------- shared GEMM skeleton pieces ----------------
// Stage a 64row x 64col bf16 tile, rows from gsrc with element stride srcStride.
static __device__ __forceinline__ void stage64(bfu* Ls, const bfu* gsrc, size_t srcStride, int t)
{
    #pragma unroll
    for (int u = 0; u < 2; u++) {
        int e   = u * 2048 + t * 8;
        int row = e >> 6;
        int col = e & 63;
        int4 v = *(const int4*)(gsrc + (size_t)row * srcStride + col);
        *(int4*)(Ls + row * 72 + col) = v;      // stride 72 hw = 144 B: 16B-aligned, <=2-way banks
    }
}

// One BK=64 step: wave (wm,wn) computes 2x2 MFMA tiles of 16x16.
static __device__ __forceinline__ void compute_step(const bfu* As, const bfu* Bs,
                                                    int wm, int wn, int l15, int quad,
                                                    f32x4 (&acc)[2][2])
{
    #pragma unroll
    for (int kk = 0; kk < 64; kk += 32) {
        bf16x8 Af[2], Bf[2];
        #pragma unroll
        for (int m = 0; m < 2; m++)
            Af[m] = *(const bf16x8*)(As + (wm * 32 + m * 16 + l15) * 72 + kk + quad * 8);
        #pragma unroll
        for (int n = 0; n < 2; n++)
            Bf[n] = *(const bf16x8*)(Bs + (wn * 32 + n * 16 + l15) * 72 + kk + quad * 8);
        #pragma unroll
        for (int m = 0; m < 2; m++)
            #pragma unroll
            for (int n = 0; n < 2; n++)
                acc[m][n] = __builtin_amdgcn_mfma_f32_16x16x32_bf16(Af[m], Bf[n], acc[m][n], 0, 0, 0);
    }
}

// ---------------- k1: Out[o][n] = Wb(640x512) . xt[b]^T, scatter into Qb/Kb/Vb ----------------
__global__ __launch_bounds__(256) void k1_proj(const bfu* __restrict__ Wb, const float* __restrict__ bcat,
                                               const bfu* __restrict__ xt,
                                               bfu* __restrict__ Qb, bfu* __restrict__ Kb, bfu* __restrict__ Vb)
{
    __shared__ bfu As[64 * 72];
    __shared__ bfu Bs[64 * 72];
    const int t  = threadIdx.x;
    const int o0 = blockIdx.x * 64;
    const int n0 = blockIdx.y * 64;
    const int b  = blockIdx.z;
    const int lane = t & 63, wv = t >> 6, wm = wv & 1, wn = wv >> 1;
    const int l15 = lane & 15, quad = lane >> 4;

    f32x4 acc[2][2];
    #pragma unroll
    for (int m = 0; m < 2; m++)
        #pragma unroll
        for (int n = 0; n < 2; n++) acc[m][n] = (f32x4){0.f, 0.f, 0.f, 0.f};

    for (int c0 = 0; c0 < NF; c0 += 64) {
        __syncthreads();
        stage64(As, Wb + (size_t)o0 * NF + c0, NF, t);                       // A[m=o][k=c]
        stage64(Bs, xt + ((size_t)(b * HW + n0)) * NF + c0, NF, t);          // B[k=c][n] = xt[n][c]
        __syncthreads();
        compute_step(As, Bs, wm, wn, l15, quad, acc);
    }

    #pragma unroll
    for (int mt = 0; mt < 2; mt++)
        #pragma unroll
        for (int nt = 0; nt < 2; nt++)
            #pragma unroll
            for (int r = 0; r < 4; r++) {
                int go = o0 + wm * 32 + mt * 16 + quad * 4 + r;      // global out-channel
                int n  = n0 + wn * 32 + nt * 16 + l15;               // spatial index
                float val = acc[mt][nt][r] + bcat[go];
                if (go < 64)
                    Qb[((size_t)(b * HW + n)) * C8 + go] = f2bu(val);            // Q: [n][c]
                else if (go < 128)
                    Kb[((size_t)(b * HW + n)) * C8 + (go - 64)] = f2bu(val);     // K: [n][c]
                else
                    Vb[((size_t)(b * NF + (go - 128))) * HW + n] = f2bu(val);    // V: [c][n]
            }
}

// ---------------- k2a: S[i][j] = sum_c K[i][c] * Q[j][c], bf16 ----------------
__global__ __launch_bounds__(256) void k2a_scores(const bfu* __restrict__ Kb, const bfu* __restrict__ Qb,
                                                  bfu* __restrict__ S)
{
    __shared__ bfu As[64 * 72];
    __shared__ bfu Bs[64 * 72];
    const int t  = threadIdx.x;
    const int i0 = blockIdx.x * 64;
    const int j0 = blockIdx.y * 64;
    const int b  = blockIdx.z;
    const int lane = t & 63, wv = t >> 6, wm = wv & 1, wn = wv >> 1;
    const int l15 = lane & 15, quad = lane >> 4;

    f32x4 acc[2][2];
    #pragma unroll
    for (int m = 0; m < 2; m++)
        #pragma unroll
        for (int n = 0; n < 2; n++) acc[m][n] = (f32x4){0.f, 0.f, 0.f, 0.f};

    stage64(As, Kb + ((size_t)(b * HW + i0)) * C8, C8, t);   // A[m=i][k=c]
    stage64(Bs, Qb + ((size_t)(b * HW + j0)) * C8, C8, t);   // B[k=c][n] = Q[j][c]
    __syncthreads();
    compute_step(As, Bs, wm, wn, l15, quad, acc);

    #pragma unroll
    for (int mt = 0; mt < 2; mt++)
        #pragma unroll
        for (int nt = 0; nt < 2; nt++)
            #pragma unroll
            for (int r = 0; r < 4; r++) {
                int i = i0 + wm * 32 + mt * 16 + quad * 4 + r;
                int j = j0 + wn * 32 + nt * 16 + l15;
                S[((size_t)(b * HW + i)) * HW + j] = f2bu(acc[mt][nt][r]);
            }
}

// ---------------- k2b: row softmax in-place on S (one row per block) ----------------
__global__ __launch_bounds__(256) void k2b_softmax(bfu* __restrict__ S)
{
    const int t = threadIdx.x;
    bfu* p = S + (size_t)blockIdx.x * HW;       // blockIdx.x = b*HW + i
    const int lane = t & 63, wv = t >> 6;
    __shared__ float red[8];

    float v[16];
    #pragma unroll
    for (int u = 0; u < 2; u++) {
        int4 raw = *(const int4*)(p + u * 2048 + t * 8);
        const bfu* h = (const bfu*)&raw;
        #pragma unroll
        for (int q = 0; q < 8; q++) v[u * 8 + q] = bu2f(h[q]);
    }
    float m = -1e30f;
    #pragma unroll
    for (int e = 0; e < 16; e++) m = fmaxf(m, v[e]);
    #pragma unroll
    for (int off = 32; off; off >>= 1) m = fmaxf(m, __shfl_xor(m, off, 64));
    if (lane == 0) red[wv] = m;
    __syncthreads();
    m = fmaxf(fmaxf(red[0], red[1]), fmaxf(red[2], red[3]));

    float s = 0.f;
    #pragma unroll
    for (int e = 0; e < 16; e++) { v[e] = __expf(v[e] - m); s += v[e]; }
    #pragma unroll
    for (int off = 32; off; off >>= 1) s += __shfl_xor(s, off, 64);
    if (lane == 0) red[4 + wv] = s;
    __syncthreads();
    s = red[4] + red[5] + red[6] + red[7];
    float inv = 1.0f / s;

    #pragma unroll
    for (int u = 0; u < 2; u++) {
        union { int4 i4; bfu h[8]; } pk;
        #pragma unroll
        for (int q = 0; q < 8; q++) pk.h[q] = f2bu(v[u * 8 + q] * inv);
        *(int4*)(p + u * 2048 + t * 8) = pk.i4;
    }
}

// ---------------- k3: out[c][i] = sum_j V[c][j]*P[i][j]; d_out = x + alpha*out ----------------
__global__ __launch_bounds__(256) void k3_pv(const bfu* __restrict__ Vb, const bfu* __restrict__ P,
                                             const float* __restrict__ x, const float* __restrict__ alpha,
                                             float* __restrict__ out)
{
    __shared__ bfu As[64 * 72];
    __shared__ bfu Bs[64 * 72];
    const int t  = threadIdx.x;
    const int c0 = blockIdx.x * 64;
    const int i0 = blockIdx.y * 64;
    const int b  = blockIdx.z;
    const int lane = t & 63, wv = t >> 6, wm = wv & 1, wn = wv >> 1;
    const int l15 = lane & 15, quad = lane >> 4;

    f32x4 acc[2][2];
    #pragma unroll
    for (int m = 0; m < 2; m++)
        #pragma unroll
        for (int n = 0; n < 2; n++) acc[m][n] = (f32x4){0.f, 0.f, 0.f, 0.f};

    for (int jb = 0; jb < HW; jb += 64) {
        __syncthreads();
        stage64(As, Vb + ((size_t)(b * NF + c0)) * HW + jb, HW, t);   // A[m=c][k=j]
        stage64(Bs, P + ((size_t)(b * HW + i0)) * HW + jb, HW, t);    // B[k=j][n] = P[i][j]
        __syncthreads();
        compute_step(As, Bs, wm, wn, l15, quad, acc);
    }

    const float al = alpha[0];
    #pragma unroll
    for (int mt = 0; mt < 2; mt++)
        #pragma unroll
        for (int nt = 0; nt < 2; nt++)
            #pragma unroll
            for (int r = 0; r < 4; r++) {
                int c = c0 + wm * 32 + mt * 16 + quad * 4 + r;
                int i = i0 + wn * 32 + nt * 16 + l15;
                size_t idx = ((size_t)(b * NF + c)) * HW + i;
                out[idx] = x[idx] + al * acc[mt][nt][r];
            }
}

extern "C" void kernel_launch(void* const* d_in, const int* in_sizes, int n_in,
                              void* d_out, int out_size, void* d_ws, size_t ws_size,
                              hipStream_t stream)
{
    const float* x     = (const float*)d_in[0];
    const float* Wq    = (const float*)d_in[1];
    const float* bq    = (const float*)d_in[2];
    const float* Wk    = (const float*)d_in[3];
    const float* bk    = (const float*)d_in[4];
    const float* Wv    = (const float*)d_in[5];
    const float* bv    = (const float*)d_in[6];
    const float* alpha = (const float*)d_in[7];
    float* out = (float*)d_out;

    char* ws = (char*)d_ws;
    bfu*   xt   = (bfu*)(ws);                       // 16 MB : [b][n][c] bf16
    bfu*   Wb   = (bfu*)(ws + (16u << 20));         // 640 KB: [640][512] bf16
    float* bcat = (float*)(ws + (17u << 20));       // 2.5 KB
    bfu*   Qb   = (bfu*)(ws + (18u << 20));         // 2 MB : [b][n][64]
    bfu*   Kb   = (bfu*)(ws + (20u << 20));         // 2 MB : [b][n][64]
    bfu*   Vb   = (bfu*)(ws + (22u << 20));         // 16 MB: [b][c][n]
    bfu*   S    = (bfu*)(ws + (38u << 20));         // 128 MB: [b][i][j] (becomes P in-place)

    k0_xt<<<dim3(HW / 64, NF / 64, BS), 256, 0, stream>>>(x, xt);
    k0_w<<<dim3(640), 256, 0, stream>>>(Wq, bq, Wk, bk, Wv, bv, Wb, bcat);
    k1_proj<<<dim3(10, HW / 64, BS), 256, 0, stream>>>(Wb, bcat, xt, Qb, Kb, Vb);
    k2a_scores<<<dim3(HW / 64, HW / 64, BS), 256, 0, stream>>>(Kb, Qb, S);
    k2b_softmax<<<dim3(BS * HW), 256, 0, stream>>>(S);
    k3_pv<<<dim3(NF / 64, HW / 64, BS), 256, 0, stream>>>(Vb, S, x, alpha, out);
}

// Round 2
// 312.111 us; speedup vs baseline: 1.3285x; 1.3285x over previous
//
#include <hip/hip_runtime.h>

#define BS 4
#define NF 512
#define HW 4096
#define C8 64

typedef unsigned short bfu;                                    // raw bf16 bits
typedef __attribute__((ext_vector_type(8))) short bf16x8;      // MFMA A/B frag (4 VGPRs)
typedef __attribute__((ext_vector_type(4))) float f32x4;       // MFMA C/D frag

static __device__ __forceinline__ bfu f2bu(float v) {
    union { unsigned int u; float f; } c; c.f = v;
    unsigned int u = c.u;
    u = u + 0x7FFFu + ((u >> 16) & 1u);   // round-to-nearest-even
    return (bfu)(u >> 16);
}
static __device__ __forceinline__ float bu2f(bfu v) {
    union { unsigned int u; float f; } c; c.u = ((unsigned int)v) << 16;
    return c.f;
}

// async global->LDS, 16 B per lane (global_load_lds_dwordx4)
static __device__ __forceinline__ void gload16(const void* g, void* l) {
    __builtin_amdgcn_global_load_lds(
        (const __attribute__((address_space(1))) unsigned int*)g,
        (__attribute__((address_space(3))) unsigned int*)l,
        16, 0, 0);
}

// ---------------- k0: x fp32 [b][c][n] -> xt bf16 [b][n][c] ----------------
__global__ __launch_bounds__(256) void k0_xt(const float* __restrict__ x, bfu* __restrict__ xt)
{
    __shared__ float T[64][68];                 // pad 68: float4 aligned, ~2-way banks
    const int t  = threadIdx.x;
    const int n0 = blockIdx.x * 64;
    const int c0 = blockIdx.y * 64;
    const int b  = blockIdx.z;

    #pragma unroll
    for (int u = 0; u < 4; u++) {
        int f4 = u * 256 + t;
        int cc = f4 >> 4;
        int n4 = (f4 & 15) << 2;
        float4 v = *(const float4*)(x + ((size_t)(b * NF + c0 + cc)) * HW + n0 + n4);
        *(float4*)&T[cc][n4] = v;
    }
    __syncthreads();
    #pragma unroll
    for (int u = 0; u < 2; u++) {
        int e8 = u * 256 + t;
        int nn = e8 >> 3;
        int c8 = (e8 & 7) << 3;
        union { int4 i4; bfu h[8]; } pk;
        #pragma unroll
        for (int q = 0; q < 8; q++) pk.h[q] = f2bu(T[c8 + q][nn]);
        *(int4*)(xt + ((size_t)(b * HW + n0 + nn)) * NF + c0 + c8) = pk.i4;
    }
}

// ---------------- k0b: Wq|Wk|Wv -> Wb bf16 [640][512]; biases -> bcat[640] ----------------
__global__ __launch_bounds__(256) void k0_w(const float* __restrict__ Wq, const float* __restrict__ bq,
                                            const float* __restrict__ Wk, const float* __restrict__ bk,
                                            const float* __restrict__ Wv, const float* __restrict__ bv,
                                            bfu* __restrict__ Wb, float* __restrict__ bcat)
{
    const int o = blockIdx.x;                   // 0..639
    const int t = threadIdx.x;
    const float* src; float bias;
    if (o < 64)       { src = Wq + (size_t)o * NF;          bias = bq[o]; }
    else if (o < 128) { src = Wk + (size_t)(o - 64) * NF;   bias = bk[o - 64]; }
    else              { src = Wv + (size_t)(o - 128) * NF;  bias = bv[o - 128]; }
    float2 v = *(const float2*)(src + t * 2);
    Wb[(size_t)o * NF + t * 2 + 0] = f2bu(v.x);
    Wb[(size_t)o * NF + t * 2 + 1] = f2bu(v.y);
    if (t == 0) bcat[o] = bias;
}

// ---------------- shared 64-tile GEMM pieces (k1/k2a) ----------------
static __device__ __forceinline__ void stage64(bfu* Ls, const bfu* gsrc, size_t srcStride, int t)
{
    #pragma unroll
    for (int u = 0; u < 2; u++) {
        int e   = u * 2048 + t * 8;
        int row = e >> 6;
        int col = e & 63;
        int4 v = *(const int4*)(gsrc + (size_t)row * srcStride + col);
        *(int4*)(Ls + row * 72 + col) = v;      // stride 72 hw = 144 B: 16B-aligned, <=2-way banks
    }
}

static __device__ __forceinline__ void compute_step(const bfu* As, const bfu* Bs,
                                                    int wm, int wn, int l15, int quad,
                                                    f32x4 (&acc)[2][2])
{
    #pragma unroll
    for (int kk = 0; kk < 64; kk += 32) {
        bf16x8 Af[2], Bf[2];
        #pragma unroll
        for (int m = 0; m < 2; m++)
            Af[m] = *(const bf16x8*)(As + (wm * 32 + m * 16 + l15) * 72 + kk + quad * 8);
        #pragma unroll
        for (int n = 0; n < 2; n++)
            Bf[n] = *(const bf16x8*)(Bs + (wn * 32 + n * 16 + l15) * 72 + kk + quad * 8);
        #pragma unroll
        for (int m = 0; m < 2; m++)
            #pragma unroll
            for (int n = 0; n < 2; n++)
                acc[m][n] = __builtin_amdgcn_mfma_f32_16x16x32_bf16(Af[m], Bf[n], acc[m][n], 0, 0, 0);
    }
}

// ---------------- k1: Out[o][n] = Wb(640x512) . xt[b]^T, scatter into Qb/Kb/Vb ----------------
__global__ __launch_bounds__(256) void k1_proj(const bfu* __restrict__ Wb, const float* __restrict__ bcat,
                                               const bfu* __restrict__ xt,
                                               bfu* __restrict__ Qb, bfu* __restrict__ Kb, bfu* __restrict__ Vb)
{
    __shared__ bfu As[64 * 72];
    __shared__ bfu Bs[64 * 72];
    const int t  = threadIdx.x;
    const int o0 = blockIdx.x * 64;
    const int n0 = blockIdx.y * 64;
    const int b  = blockIdx.z;
    const int lane = t & 63, wv = t >> 6, wm = wv & 1, wn = wv >> 1;
    const int l15 = lane & 15, quad = lane >> 4;

    f32x4 acc[2][2];
    #pragma unroll
    for (int m = 0; m < 2; m++)
        #pragma unroll
        for (int n = 0; n < 2; n++) acc[m][n] = (f32x4){0.f, 0.f, 0.f, 0.f};

    for (int c0 = 0; c0 < NF; c0 += 64) {
        __syncthreads();
        stage64(As, Wb + (size_t)o0 * NF + c0, NF, t);                       // A[m=o][k=c]
        stage64(Bs, xt + ((size_t)(b * HW + n0)) * NF + c0, NF, t);          // B[k=c][n] = xt[n][c]
        __syncthreads();
        compute_step(As, Bs, wm, wn, l15, quad, acc);
    }

    #pragma unroll
    for (int mt = 0; mt < 2; mt++)
        #pragma unroll
        for (int nt = 0; nt < 2; nt++)
            #pragma unroll
            for (int r = 0; r < 4; r++) {
                int go = o0 + wm * 32 + mt * 16 + quad * 4 + r;      // global out-channel
                int n  = n0 + wn * 32 + nt * 16 + l15;               // spatial index
                float val = acc[mt][nt][r] + bcat[go];
                if (go < 64)
                    Qb[((size_t)(b * HW + n)) * C8 + go] = f2bu(val);            // Q: [n][c]
                else if (go < 128)
                    Kb[((size_t)(b * HW + n)) * C8 + (go - 64)] = f2bu(val);     // K: [n][c]
                else
                    Vb[((size_t)(b * NF + (go - 128))) * HW + n] = f2bu(val);    // V: [c][n]
            }
}

// ---------------- k2a: S[i][j] = sum_c K[i][c] * Q[j][c], bf16 ----------------
__global__ __launch_bounds__(256) void k2a_scores(const bfu* __restrict__ Kb, const bfu* __restrict__ Qb,
                                                  bfu* __restrict__ S)
{
    __shared__ bfu As[64 * 72];
    __shared__ bfu Bs[64 * 72];
    const int t  = threadIdx.x;
    const int i0 = blockIdx.x * 64;
    const int j0 = blockIdx.y * 64;
    const int b  = blockIdx.z;
    const int lane = t & 63, wv = t >> 6, wm = wv & 1, wn = wv >> 1;
    const int l15 = lane & 15, quad = lane >> 4;

    f32x4 acc[2][2];
    #pragma unroll
    for (int m = 0; m < 2; m++)
        #pragma unroll
        for (int n = 0; n < 2; n++) acc[m][n] = (f32x4){0.f, 0.f, 0.f, 0.f};

    stage64(As, Kb + ((size_t)(b * HW + i0)) * C8, C8, t);   // A[m=i][k=c]
    stage64(Bs, Qb + ((size_t)(b * HW + j0)) * C8, C8, t);   // B[k=c][n] = Q[j][c]
    __syncthreads();
    compute_step(As, Bs, wm, wn, l15, quad, acc);

    #pragma unroll
    for (int mt = 0; mt < 2; mt++)
        #pragma unroll
        for (int nt = 0; nt < 2; nt++)
            #pragma unroll
            for (int r = 0; r < 4; r++) {
                int i = i0 + wm * 32 + mt * 16 + quad * 4 + r;
                int j = j0 + wn * 32 + nt * 16 + l15;
                S[((size_t)(b * HW + i)) * HW + j] = f2bu(acc[mt][nt][r]);
            }
}

// ---------------- k2b: row softmax in-place on S (one row per block) ----------------
__global__ __launch_bounds__(256) void k2b_softmax(bfu* __restrict__ S)
{
    const int t = threadIdx.x;
    bfu* p = S + (size_t)blockIdx.x * HW;       // blockIdx.x = b*HW + i
    const int lane = t & 63, wv = t >> 6;
    __shared__ float red[8];

    float v[16];
    #pragma unroll
    for (int u = 0; u < 2; u++) {
        int4 raw = *(const int4*)(p + u * 2048 + t * 8);
        const bfu* h = (const bfu*)&raw;
        #pragma unroll
        for (int q = 0; q < 8; q++) v[u * 8 + q] = bu2f(h[q]);
    }
    float m = -1e30f;
    #pragma unroll
    for (int e = 0; e < 16; e++) m = fmaxf(m, v[e]);
    #pragma unroll
    for (int off = 32; off; off >>= 1) m = fmaxf(m, __shfl_xor(m, off, 64));
    if (lane == 0) red[wv] = m;
    __syncthreads();
    m = fmaxf(fmaxf(red[0], red[1]), fmaxf(red[2], red[3]));

    float s = 0.f;
    #pragma unroll
    for (int e = 0; e < 16; e++) { v[e] = __expf(v[e] - m); s += v[e]; }
    #pragma unroll
    for (int off = 32; off; off >>= 1) s += __shfl_xor(s, off, 64);
    if (lane == 0) red[4 + wv] = s;
    __syncthreads();
    s = red[4] + red[5] + red[6] + red[7];
    float inv = 1.0f / s;

    #pragma unroll
    for (int u = 0; u < 2; u++) {
        union { int4 i4; bfu h[8]; } pk;
        #pragma unroll
        for (int q = 0; q < 8; q++) pk.h[q] = f2bu(v[u * 8 + q] * inv);
        *(int4*)(p + u * 2048 + t * 8) = pk.i4;
    }
}

// ---------------- k3: out[c][i] = sum_j V[c][j]*P[i][j]; d_out = x + alpha*out ----------------
// m97-style: 128x128 output tile (c x i), BK=64, global_load_lds width-16 staging,
// unpadded LDS (required: lane-ordered contiguous destination), 4 waves in 2x2,
// each wave 4x4 tiles of 16x16x32 MFMA.
__global__ __launch_bounds__(256) void k3_pv(const bfu* __restrict__ Vb, const bfu* __restrict__ P,
                                             const float* __restrict__ x, const float* __restrict__ alpha,
                                             float* __restrict__ out)
{
    __shared__ bfu As[128 * 64];    // V tile: rows c (128), cols j (64)   16 KB
    __shared__ bfu Bs[128 * 64];    // P tile: rows i (128), cols j (64)   16 KB
    const int t  = threadIdx.x;
    const int c0 = blockIdx.x * 128;
    const int i0 = blockIdx.y * 128;
    const int b  = blockIdx.z;
    const int lane = t & 63, wv = t >> 6;
    const int wm = wv & 1, wn = wv >> 1;            // 2x2 waves over 128x128
    const int l15 = lane & 15, quad = lane >> 4;

    // staging coords: thread t loads 8 bf16 (16B) per pass; 4 passes cover 128x64
    const int srow = t >> 3;          // 0..31 within pass, rows advance by 32/pass
    const int scol = (t & 7) * 8;     // 0,8,..,56

    const bfu* gA = Vb + ((size_t)(b * NF + c0 + srow)) * HW + scol;
    const bfu* gB = P  + ((size_t)(b * HW + i0 + srow)) * HW + scol;
    bfu* lA = As + t * 8;             // lane-ordered contiguous: row srow, col scol
    bfu* lB = Bs + t * 8;

    f32x4 acc[4][4];
    #pragma unroll
    for (int m = 0; m < 4; m++)
        #pragma unroll
        for (int n = 0; n < 4; n++) acc[m][n] = (f32x4){0.f, 0.f, 0.f, 0.f};

    for (int jb = 0; jb < HW; jb += 64) {
        __syncthreads();
        #pragma unroll
        for (int p = 0; p < 4; p++) {
            gload16(gA + (size_t)(p * 32) * HW + jb, lA + p * 2048);
            gload16(gB + (size_t)(p * 32) * HW + jb, lB + p * 2048);
        }
        __syncthreads();

        #pragma unroll
        for (int kk = 0; kk < 64; kk += 32) {
            bf16x8 Af[4], Bf[4];
            #pragma unroll
            for (int m = 0; m < 4; m++)
                Af[m] = *(const bf16x8*)(As + (wm * 64 + m * 16 + l15) * 64 + kk + quad * 8);
            #pragma unroll
            for (int n = 0; n < 4; n++)
                Bf[n] = *(const bf16x8*)(Bs + (wn * 64 + n * 16 + l15) * 64 + kk + quad * 8);
            #pragma unroll
            for (int m = 0; m < 4; m++)
                #pragma unroll
                for (int n = 0; n < 4; n++)
                    acc[m][n] = __builtin_amdgcn_mfma_f32_16x16x32_bf16(Af[m], Bf[n], acc[m][n], 0, 0, 0);
        }
    }

    const float al = alpha[0];
    #pragma unroll
    for (int mt = 0; mt < 4; mt++)
        #pragma unroll
        for (int nt = 0; nt < 4; nt++)
            #pragma unroll
            for (int r = 0; r < 4; r++) {
                int c = c0 + wm * 64 + mt * 16 + quad * 4 + r;
                int i = i0 + wn * 64 + nt * 16 + l15;
                size_t idx = ((size_t)(b * NF + c)) * HW + i;
                out[idx] = x[idx] + al * acc[mt][nt][r];
            }
}

extern "C" void kernel_launch(void* const* d_in, const int* in_sizes, int n_in,
                              void* d_out, int out_size, void* d_ws, size_t ws_size,
                              hipStream_t stream)
{
    const float* x     = (const float*)d_in[0];
    const float* Wq    = (const float*)d_in[1];
    const float* bq    = (const float*)d_in[2];
    const float* Wk    = (const float*)d_in[3];
    const float* bk    = (const float*)d_in[4];
    const float* Wv    = (const float*)d_in[5];
    const float* bv    = (const float*)d_in[6];
    const float* alpha = (const float*)d_in[7];
    float* out = (float*)d_out;

    char* ws = (char*)d_ws;
    bfu*   xt   = (bfu*)(ws);                       // 16 MB : [b][n][c] bf16
    bfu*   Wb   = (bfu*)(ws + (16u << 20));         // 640 KB: [640][512] bf16
    float* bcat = (float*)(ws + (17u << 20));       // 2.5 KB
    bfu*   Qb   = (bfu*)(ws + (18u << 20));         // 2 MB : [b][n][64]
    bfu*   Kb   = (bfu*)(ws + (20u << 20));         // 2 MB : [b][n][64]
    bfu*   Vb   = (bfu*)(ws + (22u << 20));         // 16 MB: [b][c][n]
    bfu*   S    = (bfu*)(ws + (38u << 20));         // 128 MB: [b][i][j] (becomes P in-place)

    k0_xt<<<dim3(HW / 64, NF / 64, BS), 256, 0, stream>>>(x, xt);
    k0_w<<<dim3(640), 256, 0, stream>>>(Wq, bq, Wk, bk, Wv, bv, Wb, bcat);
    k1_proj<<<dim3(10, HW / 64, BS), 256, 0, stream>>>(Wb, bcat, xt, Qb, Kb, Vb);
    k2a_scores<<<dim3(HW / 64, HW / 64, BS), 256, 0, stream>>>(Kb, Qb, S);
    k2b_softmax<<<dim3(BS * HW), 256, 0, stream>>>(S);
    k3_pv<<<dim3(NF / 128, HW / 128, BS), 256, 0, stream>>>(Vb, S, x, alpha, out);
}